// Round 5
// baseline (159.811 us; speedup 1.0000x reference)
//
#include <hip/hip_runtime.h>
#include <hip/hip_bf16.h>

// Math (validated rounds 2-4, all passed): softmax rows sum to 1 =>
//   out = (x @ WvSum) @ WoSum + bo,  Wq/Wk dead.
// Numerics: split-bf16 (a=ah+al), product ah*bh + ah*bl + al*bh (absmax 0.125, passed).
// This round: single fused kernel per 32-row strip (the op is row-separable):
//   phase1: tmp_strip = x_strip @ WvS  (waves split K, A-frags direct from global x)
//   LDS reduce -> bf16 h/l A-frags
//   phase2: out_strip = tmp_strip @ WoS + bo  (waves split N, B-frags L2->reg)
// Kills the tmp HBM roundtrip, one dispatch, and 14/16 barriers vs round 4.

typedef __attribute__((ext_vector_type(8))) short bf16x8;
typedef __attribute__((ext_vector_type(4))) float f32x4;

__device__ __forceinline__ unsigned short f2bf(float f) {  // fp32 -> bf16 RNE
  unsigned int u = __builtin_bit_cast(unsigned int, f);
  u += 0x7FFFu + ((u >> 16) & 1u);
  return (unsigned short)(u >> 16);
}
__device__ __forceinline__ float bf2f(unsigned short b) {
  unsigned int u = ((unsigned int)b) << 16;
  return __builtin_bit_cast(float, u);
}
__device__ __forceinline__ unsigned int pack2(unsigned short a, unsigned short b) {
  return (unsigned int)a | ((unsigned int)b << 16);
}
__device__ __forceinline__ void split2(float a, float b, unsigned int& hi, unsigned int& lo) {
  unsigned short ha = f2bf(a), hb = f2bf(b);
  hi = pack2(ha, hb);
  lo = pack2(f2bf(a - bf2f(ha)), f2bf(b - bf2f(hb)));
}
__device__ __forceinline__ bf16x8 asbf(uint4 u) { return __builtin_bit_cast(bf16x8, u); }

// ---------------- prep: weight sums -> B operands in MFMA-frag order ---------
// (verbatim from round 4 — verified by passing rounds 3/4)
// BvF frag layout (uint4 index): ((s*4 + ctg)*2 + hl)*64 + lane
//   holds WvSum[k = s*32 + (lane>>4)*8 + j][col = ctg*16 + (lane&15)], j=0..7
// BoF frag layout (uint4 index): ((g*2 + kk)*2 + hl)*64 + lane
//   holds WoSum[k = kk*32 + (lane>>4)*8 + j][e = g*16 + (lane&15)], j=0..7
__global__ __launch_bounds__(256) void prep(const float* __restrict__ Wv,
                                            const float* __restrict__ Wo,
                                            unsigned short* __restrict__ BvF,
                                            unsigned short* __restrict__ BoF) {
  const int b = blockIdx.x, t = threadIdx.x;
  const int l = t & 63, lr = l & 15, lk = (l >> 4) << 3;
  if (b < 32) {                 // Bv frags, k-slice s = b
    const int s = b, ctg = t >> 6;
    const int d = (ctg << 4) + lr;
    const int k0 = (s << 5) + lk;
    float sum[8] = {};
#pragma unroll
    for (int h = 0; h < 16; ++h)
#pragma unroll
      for (int j = 0; j < 8; ++j)
        sum[j] += Wv[(k0 + j) * 1024 + h * 64 + d];
    unsigned short hh[8], ll[8];
#pragma unroll
    for (int j = 0; j < 8; ++j) {
      hh[j] = f2bf(sum[j]);
      ll[j] = f2bf(sum[j] - bf2f(hh[j]));
    }
    const int base = ((s * 4 + ctg) * 2) * 64 + l;
    ((uint4*)BvF)[base] = make_uint4(pack2(hh[0], hh[1]), pack2(hh[2], hh[3]),
                                     pack2(hh[4], hh[5]), pack2(hh[6], hh[7]));
    ((uint4*)BvF)[base + 64] = make_uint4(pack2(ll[0], ll[1]), pack2(ll[2], ll[3]),
                                          pack2(ll[4], ll[5]), pack2(ll[6], ll[7]));
  } else {                      // Bo frags, col-frag g = b-32
    const int g = b - 32;
    const int kk = t >> 7, jh = (t >> 6) & 1;
    const int e = (g << 4) + lr;
    const int kb = (kk << 5) + lk + (jh << 2);
    float sum[4] = {};
#pragma unroll
    for (int h = 0; h < 16; ++h)
#pragma unroll
      for (int j = 0; j < 4; ++j)
        sum[j] += Wo[(h * 64 + kb + j) * 1024 + e];
    unsigned short hh[4], ll[4];
#pragma unroll
    for (int j = 0; j < 4; ++j) {
      hh[j] = f2bf(sum[j]);
      ll[j] = f2bf(sum[j] - bf2f(hh[j]));
    }
    const int base = ((((g * 2 + kk) * 2) * 64 + l) << 1) + jh;
    ((uint2*)BoF)[base] = make_uint2(pack2(hh[0], hh[1]), pack2(hh[2], hh[3]));
    ((uint2*)BoF)[base + 128] = make_uint2(pack2(ll[0], ll[1]), pack2(ll[2], ll[3]));
  }
}

// ---------------- fused: out = (x @ WvS) @ WoS + bo, per 32-row strip --------
// 512 thr = 8 waves = (rh:2) x (q:4). Phase1: wave (rh,q) does rows rh*16..+15,
// K-slice q*256..+255, all 64 cols. Phase2: same rows, col-quarter q*256..+255.
__global__ __launch_bounds__(512, 4) void fused(const float* __restrict__ x,
                                                const unsigned short* __restrict__ BvF,
                                                const unsigned short* __restrict__ BoF,
                                                const float* __restrict__ bo,
                                                float* __restrict__ out) {
  __shared__ float red[2][4][16][64];                       // 32 KB partials
  __shared__ unsigned short Ah[2][16][72], Al[2][16][72];   // 9 KB (pad 72: 2-way = free)
  const int t = threadIdx.x, w = t >> 6, l = t & 63;
  const int rh = w >> 2, q = w & 3;
  const int lr = l & 15, lk8 = (l >> 4) << 3;
  const int r0 = (int)blockIdx.x << 5;
  const int rb = r0 + (rh << 4);

  // ---- phase 1: partial tmp strip in acc, K-slice per wave ----
  // A direct from global x: lane l = row lr, k contiguous at (l>>4)*8 (128-B
  // row segments, full coalescing). Layout verified by rounds 3/4 passing.
  {
    const float* xp = &x[(rb + lr) * 1024 + (q << 8) + lk8];
    const uint4* bp = (const uint4*)BvF;
    f32x4 acc[4] = {};
    float4 xv[2][2];
    uint4 br[2][8];
    // prologue kc=0
    xv[0][0] = *(const float4*)(xp);
    xv[0][1] = *(const float4*)(xp + 4);
#pragma unroll
    for (int ct = 0; ct < 4; ++ct)
#pragma unroll
      for (int hl = 0; hl < 2; ++hl)
        br[0][ct * 2 + hl] = bp[(((q * 8) * 4 + ct) * 2 + hl) * 64 + l];
#pragma unroll
    for (int kc = 0; kc < 8; ++kc) {
      const int cur = kc & 1;
      if (kc + 1 < 8) {  // depth-1 prefetch: next x (HBM) + next B (L2)
        const float* xq = xp + (kc + 1) * 32;
        xv[cur ^ 1][0] = *(const float4*)(xq);
        xv[cur ^ 1][1] = *(const float4*)(xq + 4);
#pragma unroll
        for (int ct = 0; ct < 4; ++ct)
#pragma unroll
          for (int hl = 0; hl < 2; ++hl)
            br[cur ^ 1][ct * 2 + hl] =
                bp[(((q * 8 + kc + 1) * 4 + ct) * 2 + hl) * 64 + l];
      }
      unsigned int h0, h1, h2, h3, q0, q1, q2, q3;
      split2(xv[cur][0].x, xv[cur][0].y, h0, q0);
      split2(xv[cur][0].z, xv[cur][0].w, h1, q1);
      split2(xv[cur][1].x, xv[cur][1].y, h2, q2);
      split2(xv[cur][1].z, xv[cur][1].w, h3, q3);
      bf16x8 ah = asbf(make_uint4(h0, h1, h2, h3));
      bf16x8 al = asbf(make_uint4(q0, q1, q2, q3));
#pragma unroll
      for (int ct = 0; ct < 4; ++ct) {
        bf16x8 bh = asbf(br[cur][ct * 2 + 0]);
        bf16x8 bl = asbf(br[cur][ct * 2 + 1]);
        acc[ct] = __builtin_amdgcn_mfma_f32_16x16x32_bf16(ah, bh, acc[ct], 0, 0, 0);
        acc[ct] = __builtin_amdgcn_mfma_f32_16x16x32_bf16(ah, bl, acc[ct], 0, 0, 0);
        acc[ct] = __builtin_amdgcn_mfma_f32_16x16x32_bf16(al, bh, acc[ct], 0, 0, 0);
      }
    }
    // C/D layout: col = l&15, row = (l>>4)*4 + j  [m89-verified, rounds 3/4 pass]
#pragma unroll
    for (int ct = 0; ct < 4; ++ct)
#pragma unroll
      for (int j = 0; j < 4; ++j)
        red[rh][q][((l >> 4) << 2) + j][(ct << 4) + lr] = acc[ct][j];
  }
  __syncthreads();
  // ---- reduce 4 K-partials, split to bf16 h/l A-frag tile ----
  {
    const int rh2 = t >> 8, row = (t >> 4) & 15, c4 = (t & 15) << 2;
    float4 s = *(const float4*)&red[rh2][0][row][c4];
    const float4 s1 = *(const float4*)&red[rh2][1][row][c4];
    const float4 s2 = *(const float4*)&red[rh2][2][row][c4];
    const float4 s3 = *(const float4*)&red[rh2][3][row][c4];
    s.x += s1.x + s2.x + s3.x;
    s.y += s1.y + s2.y + s3.y;
    s.z += s1.z + s2.z + s3.z;
    s.w += s1.w + s2.w + s3.w;
    unsigned int h01, l01, h23, l23;
    split2(s.x, s.y, h01, l01);
    split2(s.z, s.w, h23, l23);
    *(uint2*)&Ah[rh2][row][c4] = make_uint2(h01, h23);
    *(uint2*)&Al[rh2][row][c4] = make_uint2(l01, l23);
  }
  __syncthreads();
  // ---- phase 2: out strip, col-quarter per wave, B frags L2->reg ----
  {
    bf16x8 afh[2], afl[2];
#pragma unroll
    for (int kk = 0; kk < 2; ++kk) {
      afh[kk] = *(const bf16x8*)&Ah[rh][lr][kk * 32 + lk8];
      afl[kk] = *(const bf16x8*)&Al[rh][lr][kk * 32 + lk8];
    }
    const uint4* bp = (const uint4*)BoF;
    uint4 brg[2][4];
    float bvr[2];
    const int g0 = q << 4;
#pragma unroll
    for (int kk = 0; kk < 2; ++kk)
#pragma unroll
      for (int hl = 0; hl < 2; ++hl)
        brg[0][kk * 2 + hl] = bp[((g0 * 2 + kk) * 2 + hl) * 64 + l];
    bvr[0] = bo[(g0 << 4) + lr];
#pragma unroll
    for (int ct = 0; ct < 16; ++ct) {
      const int cur = ct & 1;
      if (ct + 1 < 16) {
        const int g = g0 + ct + 1;
#pragma unroll
        for (int kk = 0; kk < 2; ++kk)
#pragma unroll
          for (int hl = 0; hl < 2; ++hl)
            brg[cur ^ 1][kk * 2 + hl] = bp[((g * 2 + kk) * 2 + hl) * 64 + l];
        bvr[cur ^ 1] = bo[(g << 4) + lr];
      }
      f32x4 a = {};
#pragma unroll
      for (int kk = 0; kk < 2; ++kk) {
        bf16x8 bh = asbf(brg[cur][kk * 2 + 0]);
        bf16x8 bl = asbf(brg[cur][kk * 2 + 1]);
        a = __builtin_amdgcn_mfma_f32_16x16x32_bf16(afh[kk], bh, a, 0, 0, 0);
        a = __builtin_amdgcn_mfma_f32_16x16x32_bf16(afh[kk], bl, a, 0, 0, 0);
        a = __builtin_amdgcn_mfma_f32_16x16x32_bf16(afl[kk], bh, a, 0, 0, 0);
      }
      const int col = (q << 8) + (ct << 4) + lr;
      const float bv = bvr[cur];
#pragma unroll
      for (int j = 0; j < 4; ++j)
        out[(rb + ((l >> 4) << 2) + j) * 1024 + col] = a[j] + bv;
    }
  }
}

extern "C" void kernel_launch(void* const* d_in, const int* in_sizes, int n_in,
                              void* d_out, int out_size, void* d_ws, size_t ws_size,
                              hipStream_t stream) {
  const float* x = (const float*)d_in[0];
  // d_in[1] = Wq, d_in[2] = Wk: mathematically dead (softmax rows sum to 1).
  const float* Wv = (const float*)d_in[3];
  const float* Wo = (const float*)d_in[4];
  const float* bo = (const float*)d_in[5];
  float* out = (float*)d_out;

  // ws (ushort): BvF 128K | BoF 128K  (512 KB total)
  unsigned short* BvF = (unsigned short*)d_ws;
  unsigned short* BoF = BvF + 131072;

  prep<<<96, 256, 0, stream>>>(Wv, Wo, BvF, BoF);
  fused<<<512, 512, 0, stream>>>(x, BvF, BoF, bo, out);
}

// Round 6
// 152.159 us; speedup vs baseline: 1.0503x; 1.0503x over previous
//
#include <hip/hip_runtime.h>
#include <hip/hip_bf16.h>

// Math (validated rounds 2-5, all passed): softmax rows sum to 1 =>
//   out = (x @ WvSum) @ WoSum + bo,  Wq/Wk dead.
//   WvSum[k][d] = sum_h Wv[k][h*64+d]  (1024x64)
//   WoSum[d][e] = sum_h Wo[h*64+d][e]  (64x1024)
// Numerics change this round: single-product fp16 MFMA (no hi/lo split).
//   fp16 = 10 mantissa bits; predicted added error ~0.01-0.03 absmax vs the
//   0.125 that already passed (split-bf16) and 0.0625 (fp32). 3x less MFMA.
// Structure: 256-thr blocks, 16-row strips (grid 1024). Phase1: 4 waves split
// K 4-ways, A-frags straight from global x (cvt f32->f16 in regs), B-frags
// L2->reg. 16KB LDS reduce. Phase2: waves split N 4-ways, B-frags L2->reg.

typedef _Float16 half8 __attribute__((ext_vector_type(8)));
typedef float f32x4 __attribute__((ext_vector_type(4)));

__device__ __forceinline__ half8 cvt8(float4 a, float4 b) {
  half8 h;
  h[0] = (_Float16)a.x; h[1] = (_Float16)a.y;
  h[2] = (_Float16)a.z; h[3] = (_Float16)a.w;
  h[4] = (_Float16)b.x; h[5] = (_Float16)b.y;
  h[6] = (_Float16)b.z; h[7] = (_Float16)b.w;
  return h;
}

// ---------------- prep: weight sums -> fp16 B-frags in MFMA lane order -------
// BvF (half8 idx): (s*4 + ctg)*64 + lane  holds WvSum[k=s*32+(l>>4)*8+j][d=ctg*16+(l&15)]
// BoF (half8 idx): (g*2 + kk)*64 + lane   holds WoSum[k=kk*32+(l>>4)*8+j][e=g*16+(l&15)]
__global__ __launch_bounds__(256) void prep(const float* __restrict__ Wv,
                                            const float* __restrict__ Wo,
                                            _Float16* __restrict__ BvF,
                                            _Float16* __restrict__ BoF) {
  const int b = blockIdx.x, t = threadIdx.x;
  const int l = t & 63, lr = l & 15, lk = (l >> 4) << 3;
  if (b < 32) {                 // Bv frags, k-slice s = b
    const int s = b, ctg = t >> 6;
    const int d = (ctg << 4) + lr;
    const int k0 = (s << 5) + lk;
    float sum[8] = {};
#pragma unroll
    for (int h = 0; h < 16; ++h)
#pragma unroll
      for (int j = 0; j < 8; ++j)
        sum[j] += Wv[(k0 + j) * 1024 + h * 64 + d];
    half8 hv;
#pragma unroll
    for (int j = 0; j < 8; ++j) hv[j] = (_Float16)sum[j];
    ((half8*)BvF)[(s * 4 + ctg) * 64 + l] = hv;
  } else {                      // Bo frags, col-frag g = b-32
    const int g = b - 32;
    const int kk = t >> 7, jh = (t >> 6) & 1;
    const int e = (g << 4) + lr;
    const int kb = (kk << 5) + lk + (jh << 2);
    float sum[4] = {};
#pragma unroll
    for (int h = 0; h < 16; ++h)
#pragma unroll
      for (int j = 0; j < 4; ++j)
        sum[j] += Wo[(h * 64 + kb + j) * 1024 + e];
    _Float16 hv[4];
#pragma unroll
    for (int j = 0; j < 4; ++j) hv[j] = (_Float16)sum[j];
    // half-offset: frag base *8, sub-half jh*4
    *(uint2*)&BoF[(((g * 2 + kk) * 64 + l) << 3) + (jh << 2)] =
        *(const uint2*)hv;
  }
}

// ---------------- fused: out_strip = (x_strip @ WvS) @ WoS + bo --------------
// 256 thr = 4 waves (q=0..3), strip = 16 rows.
// Phase1: wave q covers K-slice q*256..+255, all 64 cols. Reduce in LDS.
// Phase2: wave q covers cols q*256..+255.
__global__ __launch_bounds__(256) void fused(const float* __restrict__ x,
                                             const _Float16* __restrict__ BvF,
                                             const _Float16* __restrict__ BoF,
                                             const float* __restrict__ bo,
                                             float* __restrict__ out) {
  __shared__ float red[4][16][64];                   // 16 KB K-partials
  __shared__ __align__(16) _Float16 Af[16][72];      // 2.3 KB fp16 A tile
  const int t = threadIdx.x, q = t >> 6, l = t & 63;
  const int lr = l & 15, lk8 = (l >> 4) << 3;
  const int r0 = (int)blockIdx.x << 4;

  // ---- phase 1 ----
  {
    const float* xp = &x[(r0 + lr) * 1024 + (q << 8) + lk8];
    const half8* bp = (const half8*)BvF;
    f32x4 acc[4] = {};
    float4 xv[2][2];
    half8 br[2][4];
    xv[0][0] = *(const float4*)(xp);
    xv[0][1] = *(const float4*)(xp + 4);
#pragma unroll
    for (int ct = 0; ct < 4; ++ct)
      br[0][ct] = bp[((q * 8) * 4 + ct) * 64 + l];
#pragma unroll
    for (int kc = 0; kc < 8; ++kc) {
      const int cur = kc & 1;
      if (kc + 1 < 8) {  // prefetch next x (HBM) + next B (L2) before compute
        const float* xq = xp + (kc + 1) * 32;
        xv[cur ^ 1][0] = *(const float4*)(xq);
        xv[cur ^ 1][1] = *(const float4*)(xq + 4);
#pragma unroll
        for (int ct = 0; ct < 4; ++ct)
          br[cur ^ 1][ct] = bp[((q * 8 + kc + 1) * 4 + ct) * 64 + l];
      }
      const half8 ah = cvt8(xv[cur][0], xv[cur][1]);
#pragma unroll
      for (int ct = 0; ct < 4; ++ct)
        acc[ct] = __builtin_amdgcn_mfma_f32_16x16x32_f16(ah, br[cur][ct], acc[ct], 0, 0, 0);
    }
    // C/D: col = l&15, row = (l>>4)*4 + j  [m89-verified, rounds 3-5 pass]
#pragma unroll
    for (int ct = 0; ct < 4; ++ct)
#pragma unroll
      for (int j = 0; j < 4; ++j)
        red[q][((l >> 4) << 2) + j][(ct << 4) + lr] = acc[ct][j];
  }
  __syncthreads();
  // ---- reduce 4 K-partials -> fp16 A tile ----
  {
    const int row = t >> 4, c4 = (t & 15) << 2;
    float4 s0 = *(const float4*)&red[0][row][c4];
    const float4 s1 = *(const float4*)&red[1][row][c4];
    const float4 s2 = *(const float4*)&red[2][row][c4];
    const float4 s3 = *(const float4*)&red[3][row][c4];
    _Float16 hv[4];
    hv[0] = (_Float16)(s0.x + s1.x + s2.x + s3.x);
    hv[1] = (_Float16)(s0.y + s1.y + s2.y + s3.y);
    hv[2] = (_Float16)(s0.z + s1.z + s2.z + s3.z);
    hv[3] = (_Float16)(s0.w + s1.w + s2.w + s3.w);
    *(uint2*)&Af[row][c4] = *(const uint2*)hv;
  }
  __syncthreads();
  // ---- phase 2: cols q*256..+255 ----
  {
    half8 afr[2];
#pragma unroll
    for (int kk = 0; kk < 2; ++kk)
      afr[kk] = *(const half8*)&Af[lr][kk * 32 + lk8];
    const half8* bp = (const half8*)BoF;
    const int g0 = q << 4;
    half8 brg[2][2];
    float bvr[2];
#pragma unroll
    for (int kk = 0; kk < 2; ++kk)
      brg[0][kk] = bp[(g0 * 2 + kk) * 64 + l];
    bvr[0] = bo[(g0 << 4) + lr];
#pragma unroll
    for (int g = 0; g < 16; ++g) {
      const int cur = g & 1;
      if (g + 1 < 16) {
#pragma unroll
        for (int kk = 0; kk < 2; ++kk)
          brg[cur ^ 1][kk] = bp[((g0 + g + 1) * 2 + kk) * 64 + l];
        bvr[cur ^ 1] = bo[((g0 + g + 1) << 4) + lr];
      }
      f32x4 a = {};
#pragma unroll
      for (int kk = 0; kk < 2; ++kk)
        a = __builtin_amdgcn_mfma_f32_16x16x32_f16(afr[kk], brg[cur][kk], a, 0, 0, 0);
      const int col = (q << 8) + (g << 4) + lr;
      const float bv = bvr[cur];
#pragma unroll
      for (int j = 0; j < 4; ++j)
        out[(r0 + ((l >> 4) << 2) + j) * 1024 + col] = a[j] + bv;
    }
  }
}

extern "C" void kernel_launch(void* const* d_in, const int* in_sizes, int n_in,
                              void* d_out, int out_size, void* d_ws, size_t ws_size,
                              hipStream_t stream) {
  const float* x = (const float*)d_in[0];
  // d_in[1] = Wq, d_in[2] = Wk: mathematically dead (softmax rows sum to 1).
  const float* Wv = (const float*)d_in[3];
  const float* Wo = (const float*)d_in[4];
  const float* bo = (const float*)d_in[5];
  float* out = (float*)d_out;

  // ws: BvF 128 KB | BoF 128 KB  (fp16 frags)
  _Float16* BvF = (_Float16*)d_ws;
  _Float16* BoF = BvF + 65536;

  prep<<<96, 256, 0, stream>>>(Wv, Wo, BvF, BoF);
  fused<<<1024, 256, 0, stream>>>(x, BvF, BoF, bo, out);
}

// Round 7
// 150.772 us; speedup vs baseline: 1.0600x; 1.0092x over previous
//
#include <hip/hip_runtime.h>
#include <hip/hip_bf16.h>

// Math (validated rounds 2-6, all passed): softmax rows sum to 1 =>
//   out = (x @ WvSum) @ WoSum + bo,  Wq/Wk dead.
//   WvSum[k][d] = sum_h Wv[k][h*64+d]  (1024x64)
//   WoSum[d][e] = sum_h Wo[h*64+d][e]  (64x1024)
// Numerics: single-product fp16 MFMA (round 6: absmax 0.125, passed).
// Round-6 counters: MfmaUtil 3%, VALUBusy 4.5%, HBM 26%, Occ 25% -> pure
// latency-bound (depth-1 prefetch). This round: MLP depth only.
//   phase1: x-prefetch ring depth 4 (4x32B in flight/lane, Little's law OK)
//   phase2: B ring depth 2 + nontemporal stores.

typedef _Float16 half8 __attribute__((ext_vector_type(8)));
typedef float f32x4 __attribute__((ext_vector_type(4)));

__device__ __forceinline__ half8 cvt8(float4 a, float4 b) {
  half8 h;
  h[0] = (_Float16)a.x; h[1] = (_Float16)a.y;
  h[2] = (_Float16)a.z; h[3] = (_Float16)a.w;
  h[4] = (_Float16)b.x; h[5] = (_Float16)b.y;
  h[6] = (_Float16)b.z; h[7] = (_Float16)b.w;
  return h;
}

// ---------------- prep: weight sums -> fp16 B-frags in MFMA lane order -------
// (verbatim round 6 — verified)
// BvF (half8 idx): (s*4 + ctg)*64 + lane  holds WvSum[k=s*32+(l>>4)*8+j][d=ctg*16+(l&15)]
// BoF (half8 idx): (g*2 + kk)*64 + lane   holds WoSum[k=kk*32+(l>>4)*8+j][e=g*16+(l&15)]
__global__ __launch_bounds__(256) void prep(const float* __restrict__ Wv,
                                            const float* __restrict__ Wo,
                                            _Float16* __restrict__ BvF,
                                            _Float16* __restrict__ BoF) {
  const int b = blockIdx.x, t = threadIdx.x;
  const int l = t & 63, lr = l & 15, lk = (l >> 4) << 3;
  if (b < 32) {                 // Bv frags, k-slice s = b
    const int s = b, ctg = t >> 6;
    const int d = (ctg << 4) + lr;
    const int k0 = (s << 5) + lk;
    float sum[8] = {};
#pragma unroll
    for (int h = 0; h < 16; ++h)
#pragma unroll
      for (int j = 0; j < 8; ++j)
        sum[j] += Wv[(k0 + j) * 1024 + h * 64 + d];
    half8 hv;
#pragma unroll
    for (int j = 0; j < 8; ++j) hv[j] = (_Float16)sum[j];
    ((half8*)BvF)[(s * 4 + ctg) * 64 + l] = hv;
  } else {                      // Bo frags, col-frag g = b-32
    const int g = b - 32;
    const int kk = t >> 7, jh = (t >> 6) & 1;
    const int e = (g << 4) + lr;
    const int kb = (kk << 5) + lk + (jh << 2);
    float sum[4] = {};
#pragma unroll
    for (int h = 0; h < 16; ++h)
#pragma unroll
      for (int j = 0; j < 4; ++j)
        sum[j] += Wo[(h * 64 + kb + j) * 1024 + e];
    _Float16 hv[4];
#pragma unroll
    for (int j = 0; j < 4; ++j) hv[j] = (_Float16)sum[j];
    *(uint2*)&BoF[(((g * 2 + kk) * 64 + l) << 3) + (jh << 2)] =
        *(const uint2*)hv;
  }
}

// ---------------- fused: out_strip = (x_strip @ WvS) @ WoS + bo --------------
// 256 thr = 4 waves (q=0..3), strip = 16 rows, grid 1024.
// Phase1: wave q covers K-slice q*256..+255, all 64 cols; x ring depth 4.
// Phase2: wave q covers cols q*256..+255; B ring depth 2; NT stores.
__global__ __launch_bounds__(256, 4) void fused(const float* __restrict__ x,
                                                const _Float16* __restrict__ BvF,
                                                const _Float16* __restrict__ BoF,
                                                const float* __restrict__ bo,
                                                float* __restrict__ out) {
  __shared__ float red[4][16][64];                   // 16 KB K-partials
  __shared__ __align__(16) _Float16 Af[16][72];      // 2.3 KB fp16 A tile
  const int t = threadIdx.x, q = t >> 6, l = t & 63;
  const int lr = l & 15, lk8 = (l >> 4) << 3;
  const int r0 = (int)blockIdx.x << 4;

  // ---- phase 1 ----
  {
    const float* xp = &x[(r0 + lr) * 1024 + (q << 8) + lk8];
    const half8* bp = (const half8*)BvF;
    f32x4 acc[4] = {};
    float4 xv[4][2];   // depth-4 x ring: 4x32B in flight per lane
    half8 br[2][4];    // depth-1 B ring (L2-resident)
#pragma unroll
    for (int p = 0; p < 4; ++p) {
      xv[p][0] = *(const float4*)(xp + p * 32);
      xv[p][1] = *(const float4*)(xp + p * 32 + 4);
    }
#pragma unroll
    for (int ct = 0; ct < 4; ++ct)
      br[0][ct] = bp[((q * 8) * 4 + ct) * 64 + l];
#pragma unroll
    for (int kc = 0; kc < 8; ++kc) {
      const int cur = kc & 3;
      const half8 ah = cvt8(xv[cur][0], xv[cur][1]);   // consume ring slot
      if (kc + 4 < 8) {                                 // refill 4 ahead
        const float* xq = xp + (kc + 4) * 32;
        xv[cur][0] = *(const float4*)(xq);
        xv[cur][1] = *(const float4*)(xq + 4);
      }
      if (kc + 1 < 8) {
#pragma unroll
        for (int ct = 0; ct < 4; ++ct)
          br[(kc + 1) & 1][ct] = bp[((q * 8 + kc + 1) * 4 + ct) * 64 + l];
      }
#pragma unroll
      for (int ct = 0; ct < 4; ++ct)
        acc[ct] = __builtin_amdgcn_mfma_f32_16x16x32_f16(ah, br[kc & 1][ct], acc[ct], 0, 0, 0);
    }
    // C/D: col = l&15, row = (l>>4)*4 + j  [m89-verified, rounds 3-6 pass]
#pragma unroll
    for (int ct = 0; ct < 4; ++ct)
#pragma unroll
      for (int j = 0; j < 4; ++j)
        red[q][((l >> 4) << 2) + j][(ct << 4) + lr] = acc[ct][j];
  }
  __syncthreads();
  // ---- reduce 4 K-partials -> fp16 A tile ----
  {
    const int row = t >> 4, c4 = (t & 15) << 2;
    float4 s0 = *(const float4*)&red[0][row][c4];
    const float4 s1 = *(const float4*)&red[1][row][c4];
    const float4 s2 = *(const float4*)&red[2][row][c4];
    const float4 s3 = *(const float4*)&red[3][row][c4];
    _Float16 hv[4];
    hv[0] = (_Float16)(s0.x + s1.x + s2.x + s3.x);
    hv[1] = (_Float16)(s0.y + s1.y + s2.y + s3.y);
    hv[2] = (_Float16)(s0.z + s1.z + s2.z + s3.z);
    hv[3] = (_Float16)(s0.w + s1.w + s2.w + s3.w);
    *(uint2*)&Af[row][c4] = *(const uint2*)hv;
  }
  __syncthreads();
  // ---- phase 2: cols q*256..+255, depth-2 B ring, NT streaming stores ----
  {
    half8 afr[2];
#pragma unroll
    for (int kk = 0; kk < 2; ++kk)
      afr[kk] = *(const half8*)&Af[lr][kk * 32 + lk8];
    const half8* bp = (const half8*)BoF;
    const int g0 = q << 4;
    half8 brg[4][2];   // ring of 4, 2 in flight
    float bvr[4];
#pragma unroll
    for (int p = 0; p < 2; ++p) {
#pragma unroll
      for (int kk = 0; kk < 2; ++kk)
        brg[p][kk] = bp[((g0 + p) * 2 + kk) * 64 + l];
      bvr[p] = bo[((g0 + p) << 4) + lr];
    }
#pragma unroll
    for (int g = 0; g < 16; ++g) {
      const int cur = g & 3;
      if (g + 2 < 16) {
        const int gn = g0 + g + 2, slot = (g + 2) & 3;
#pragma unroll
        for (int kk = 0; kk < 2; ++kk)
          brg[slot][kk] = bp[(gn * 2 + kk) * 64 + l];
        bvr[slot] = bo[(gn << 4) + lr];
      }
      f32x4 a = {};
#pragma unroll
      for (int kk = 0; kk < 2; ++kk)
        a = __builtin_amdgcn_mfma_f32_16x16x32_f16(afr[kk], brg[cur][kk], a, 0, 0, 0);
      const int col = (q << 8) + (g << 4) + lr;
      const float bv = bvr[cur];
#pragma unroll
      for (int j = 0; j < 4; ++j)
        __builtin_nontemporal_store(a[j] + bv,
            &out[(r0 + ((l >> 4) << 2) + j) * 1024 + col]);
    }
  }
}

extern "C" void kernel_launch(void* const* d_in, const int* in_sizes, int n_in,
                              void* d_out, int out_size, void* d_ws, size_t ws_size,
                              hipStream_t stream) {
  const float* x = (const float*)d_in[0];
  // d_in[1] = Wq, d_in[2] = Wk: mathematically dead (softmax rows sum to 1).
  const float* Wv = (const float*)d_in[3];
  const float* Wo = (const float*)d_in[4];
  const float* bo = (const float*)d_in[5];
  float* out = (float*)d_out;

  // ws: BvF 128 KB | BoF 128 KB  (fp16 frags)
  _Float16* BvF = (_Float16*)d_ws;
  _Float16* BoF = BvF + 65536;

  prep<<<96, 256, 0, stream>>>(Wv, Wo, BvF, BoF);
  fused<<<1024, 256, 0, stream>>>(x, BvF, BoF, bo, out);
}